// Round 3
// baseline (300.234 us; speedup 1.0000x reference)
//
#include <hip/hip_runtime.h>
#include <cstdint>
#include <cstddef>

// Quantized linear (Brevitas-style int8 per-tensor symmetric).
//   x [N=32768, K=1024] f32, w [M=1024, K=1024] f32, bias [M] f32.
//   sx = max|x|/127, sw = max|w|/127; qx = clip(rne(x/sx)) int8, qw likewise
//   out[n,m] = (sum_k qx[n,k]*qw[m,k]) * sx*sw + bias[m]   (f32)
//
// ws layout:
//   [0..7]      2 floats: final amax_x, amax_w  (written by quant kernel)
//   [64..]      per-block partial maxes (NBX for x, NBW for w)
//   [8192..]    qx (N*K int8), then qw (M*K int8)

typedef int v4i __attribute__((ext_vector_type(4)));

#define QMAXF 127.0f
#define KDIM 1024
#define MDIM 1024
#define NBX 1024  // absmax blocks for x
#define NBW 64    // absmax blocks for w

// ---------------- pass 1: per-block partial |max| (no atomics, no init) ----
__global__ __launch_bounds__(256) void absmax_partial(
    const float4* __restrict__ x, int nx4,
    const float4* __restrict__ w, int nw4,
    float* __restrict__ partials) {
  const int b = blockIdx.x;
  const bool isw = (b >= NBX);
  const float4* __restrict__ p = isw ? w : x;
  const int n4 = isw ? nw4 : nx4;
  const int nb = isw ? NBW : NBX;
  const int bb = isw ? (b - NBX) : b;
  const int stride = nb * 256;

  float m0 = 0.f, m1 = 0.f, m2 = 0.f, m3 = 0.f;
  int i = bb * 256 + threadIdx.x;
  for (; i + 3 * stride < n4; i += 4 * stride) {
    float4 v0 = p[i], v1 = p[i + stride], v2 = p[i + 2 * stride],
           v3 = p[i + 3 * stride];
    m0 = fmaxf(m0, fmaxf(fmaxf(fabsf(v0.x), fabsf(v0.y)),
                         fmaxf(fabsf(v0.z), fabsf(v0.w))));
    m1 = fmaxf(m1, fmaxf(fmaxf(fabsf(v1.x), fabsf(v1.y)),
                         fmaxf(fabsf(v1.z), fabsf(v1.w))));
    m2 = fmaxf(m2, fmaxf(fmaxf(fabsf(v2.x), fabsf(v2.y)),
                         fmaxf(fabsf(v2.z), fabsf(v2.w))));
    m3 = fmaxf(m3, fmaxf(fmaxf(fabsf(v3.x), fabsf(v3.y)),
                         fmaxf(fabsf(v3.z), fabsf(v3.w))));
  }
  for (; i < n4; i += stride) {
    float4 v = p[i];
    m0 = fmaxf(m0, fmaxf(fmaxf(fabsf(v.x), fabsf(v.y)),
                         fmaxf(fabsf(v.z), fabsf(v.w))));
  }
  float m = fmaxf(fmaxf(m0, m1), fmaxf(m2, m3));
  for (int off = 32; off; off >>= 1) m = fmaxf(m, __shfl_down(m, off, 64));
  __shared__ float wm[4];
  const int lane = threadIdx.x & 63, wid = threadIdx.x >> 6;
  if (lane == 0) wm[wid] = m;
  __syncthreads();
  if (threadIdx.x == 0)
    partials[b] = fmaxf(fmaxf(wm[0], wm[1]), fmaxf(wm[2], wm[3]));
}

// ---------------- pass 2: reduce partials + quantize ----------------------
// Fully coalesced: one float4 per lane per chunk, dword code-store per lane.
// No clamps needed: |v| <= amax  =>  |v * (127/amax)| <= 127*(1+2eps) < 127.5
// so round-nearest-even can never produce +-128.
__global__ __launch_bounds__(256) void quant2(
    const float4* __restrict__ x, int nx4,
    const float4* __restrict__ w, int nw4,
    const float* __restrict__ partials,
    unsigned* __restrict__ qx, unsigned* __restrict__ qw,
    float* __restrict__ amax_out) {
  const int sel = blockIdx.y;
  const float* pp = partials + (sel ? NBX : 0);
  const int np = sel ? NBW : NBX;
  float m = 0.f;
  for (int i = threadIdx.x; i < np; i += 256) m = fmaxf(m, pp[i]);
  for (int off = 32; off; off >>= 1) m = fmaxf(m, __shfl_down(m, off, 64));
  __shared__ float wm[4];
  __shared__ float bmax;
  const int lane = threadIdx.x & 63, wid = threadIdx.x >> 6;
  if (lane == 0) wm[wid] = m;
  __syncthreads();
  if (threadIdx.x == 0) {
    float bm = fmaxf(fmaxf(wm[0], wm[1]), fmaxf(wm[2], wm[3]));
    bmax = bm;
    if (blockIdx.x == 0) amax_out[sel] = bm;  // publish for GEMM epilogue
  }
  __syncthreads();
  const float r = QMAXF / bmax;

  const float4* __restrict__ p = sel ? w : x;
  const int n4 = sel ? nw4 : nx4;
  unsigned* __restrict__ q = sel ? qw : qx;

#define QPK(V)                                              \
  (((unsigned)(((int)rintf((V).x * r)) & 255)) |            \
   ((unsigned)(((int)rintf((V).y * r)) & 255) << 8) |       \
   ((unsigned)(((int)rintf((V).z * r)) & 255) << 16) |      \
   ((unsigned)(((int)rintf((V).w * r)) & 255) << 24))
  for (int base = blockIdx.x * 1024 + threadIdx.x; base < n4;
       base += gridDim.x * 1024) {
    // 4 block-strided chunks; every load/store wave-contiguous
    if (base + 768 < n4) {
      float4 v0 = p[base], v1 = p[base + 256], v2 = p[base + 512],
             v3 = p[base + 768];
      q[base] = QPK(v0);
      q[base + 256] = QPK(v1);
      q[base + 512] = QPK(v2);
      q[base + 768] = QPK(v3);
    } else {
      for (int i = base; i < n4; i += 256) {
        float4 v = p[i];
        q[i] = QPK(v);
      }
    }
  }
#undef QPK
}

// ---------------- pass 3: i8 MFMA GEMM, 128x128 tile, BK=128, swizzled -----
__device__ __forceinline__ void ld_lds16(const void* g, void* l) {
  __builtin_amdgcn_global_load_lds(
      (__attribute__((address_space(1))) void*)(void*)g,
      (__attribute__((address_space(3))) void*)l, 16, 0, 0);
}

// LDS layout: [128 rows][8 segs of 16B], physical seg = logical seg ^ (row&7).
// Swizzle applied on the *global source* side during global_load_lds (dest is
// forced wave-uniform-base + lane*16). Fragment reads then spread evenly
// across bank groups (max 2-way aliasing = free per m136).
__global__ __launch_bounds__(256) void gemm_i8(
    const char* __restrict__ qx, const char* __restrict__ qw,
    const float* __restrict__ bias, const float* __restrict__ amax,
    float* __restrict__ out) {
  __shared__ __align__(16) char smA[128 * 128];
  __shared__ __align__(16) char smB[128 * 128];

  const int tid = threadIdx.x;
  const int wave = tid >> 6;
  const int lane = tid & 63;
  const int bm = blockIdx.x;  // M/128 = 8   (fastest -> XCD k owns bm=k)
  const int bn = blockIdx.y;  // N/128 = 256
  const int wn = wave >> 1;
  const int wm = wave & 1;

  const char* xb = qx + (size_t)(bn * 128) * KDIM;
  const char* wb = qw + (size_t)(bm * 128) * KDIM;

  v4i acc[4][4] = {};

  const int lrow = lane >> 3;          // 0..7 within an 8-row staging slab
  const int sgx = (lane & 7) ^ lrow;   // swizzled source segment

  for (int kt = 0; kt < 8; ++kt) {
    const int kb = kt * 128;
#pragma unroll
    for (int c = 0; c < 4; ++c) {
      const int rbase = c * 32 + wave * 8;  // 8 rows per wave-call
      ld_lds16(xb + (size_t)(rbase + lrow) * KDIM + kb + sgx * 16,
               smA + rbase * 128);
      ld_lds16(wb + (size_t)(rbase + lrow) * KDIM + kb + sgx * 16,
               smB + rbase * 128);
    }
    __syncthreads();  // vmcnt(0) drain + barrier: tiles visible

#pragma unroll
    for (int kc = 0; kc < 2; ++kc) {
      const int s = kc * 4 + (lane >> 4);  // logical 16B seg in row
      v4i a[4], b[4];
#pragma unroll
      for (int i = 0; i < 4; ++i) {
        const int r = wn * 64 + i * 16 + (lane & 15);
        a[i] = *(const v4i*)(smA + r * 128 + ((s ^ (r & 7)) * 16));
      }
#pragma unroll
      for (int j = 0; j < 4; ++j) {
        const int r = wm * 64 + j * 16 + (lane & 15);
        b[j] = *(const v4i*)(smB + r * 128 + ((s ^ (r & 7)) * 16));
      }
#pragma unroll
      for (int i = 0; i < 4; ++i)
#pragma unroll
        for (int j = 0; j < 4; ++j)
          acc[i][j] = __builtin_amdgcn_mfma_i32_16x16x64_i8(a[i], b[j],
                                                            acc[i][j], 0, 0, 0);
    }
    __syncthreads();
  }

  // epilogue: C/D layout col=lane&15 (m), row=(lane>>4)*4+reg (n)
  const float s = (amax[0] / QMAXF) * (amax[1] / QMAXF);
  const int mcol = bm * 128 + wm * 64 + (lane & 15);
  const int nbase = bn * 128 + wn * 64 + ((lane >> 4) << 2);
  float bv[4];
#pragma unroll
  for (int j = 0; j < 4; ++j) bv[j] = bias[mcol + j * 16];
#pragma unroll
  for (int i = 0; i < 4; ++i) {
#pragma unroll
    for (int r = 0; r < 4; ++r) {
      const int n = nbase + i * 16 + r;
      float* orow = out + (size_t)n * MDIM + mcol;
#pragma unroll
      for (int j = 0; j < 4; ++j)
        __builtin_nontemporal_store((float)acc[i][j][r] * s + bv[j],
                                    orow + j * 16);
    }
  }
}

extern "C" void kernel_launch(void* const* d_in, const int* in_sizes, int n_in,
                              void* d_out, int out_size, void* d_ws, size_t ws_size,
                              hipStream_t stream) {
  const float* x = (const float*)d_in[0];
  const float* w = (const float*)d_in[1];
  const float* bias = (const float*)d_in[2];
  float* out = (float*)d_out;

  const int NX = in_sizes[0];  // N*K = 33554432
  const int NW = in_sizes[1];  // M*K = 1048576
  const int N = NX / KDIM;     // 32768

  float* amax = (float*)d_ws;
  float* partials = (float*)((char*)d_ws + 64);
  char* qx = (char*)d_ws + 8192;
  char* qw = qx + (size_t)NX;

  absmax_partial<<<NBX + NBW, 256, 0, stream>>>(
      (const float4*)x, NX / 4, (const float4*)w, NW / 4, partials);

  dim3 qgrid(1024, 2);
  quant2<<<qgrid, 256, 0, stream>>>((const float4*)x, NX / 4,
                                    (const float4*)w, NW / 4, partials,
                                    (unsigned*)qx, (unsigned*)qw, amax);

  dim3 ggrid(MDIM / 128, N / 128);
  gemm_i8<<<ggrid, 256, 0, stream>>>(qx, qw, bias, amax, out);
}